// Round 1
// baseline (237.752 us; speedup 1.0000x reference)
//
#include <hip/hip_runtime.h>
#include <math.h>

// PCEN: x[B=64, C=128, T=4000] fp32.
// smooth[0]=x[0]; smooth[t]=(1-s)*smooth[t-1]+s*x[t], s=0.025
// out = sqrt(x/(smooth+1e-6)^0.98 + 2) - sqrt(2)
//
// One block (256 threads) per channel. Constant-coefficient linear recurrence
// -> chunked affine scan: each thread owns 16 contiguous elements, local scan
// with zero init gives affine map (A = 0.975^16, B = local result); block scan
// over maps (shuffle intra-wave, tiny LDS across 4 waves); replay with true init.

constexpr int   TLEN  = 4000;
constexpr int   CHUNK = 16;
constexpr int   NTH   = 256;      // threads/block; 250 active (250*16 = 4000)
constexpr float S_C   = 0.025f;
constexpr float A_C   = 1.0f - S_C;  // 0.975
constexpr float ALPHA = 0.98f;
constexpr float EPS_C = 1e-6f;
constexpr float SQRT2 = 1.41421356237309515f;

__global__ __launch_bounds__(NTH) void pcen_kernel(const float* __restrict__ x,
                                                   float* __restrict__ out) {
    const int    ch   = blockIdx.x;
    const size_t base = (size_t)ch * TLEN;
    const int    tid  = threadIdx.x;
    const int    lane = tid & 63;
    const int    wv   = tid >> 6;
    const bool   active = (tid * CHUNK < TLEN);   // tid < 250

    // ---- load 16 contiguous floats (4x float4; channel base is 16B aligned) ----
    float v[CHUNK];
    const float4* __restrict__ x4 = (const float4*)(x + base);
    if (active) {
#pragma unroll
        for (int q = 0; q < 4; ++q) {
            float4 r = x4[tid * 4 + q];
            v[q * 4 + 0] = r.x; v[q * 4 + 1] = r.y;
            v[q * 4 + 2] = r.z; v[q * 4 + 3] = r.w;
        }
    } else {
#pragma unroll
        for (int j = 0; j < CHUNK; ++j) v[j] = 0.0f;
    }

    // ---- local scan with zero init: value(init) = A*init + B ----
    float sm = 0.0f;
#pragma unroll
    for (int j = 0; j < CHUNK; ++j) {
        float b = S_C * v[j];
        if (tid == 0 && j == 0) b = v[0];   // smooth[0] = x[0]
        sm = fmaf(A_C, sm, b);
    }
    float a16 = 1.0f;
#pragma unroll
    for (int i = 0; i < CHUNK; ++i) a16 *= A_C;   // constant-folded 0.975^16

    float A = a16;   // affine map of this thread's chunk
    float B = sm;

    // ---- inclusive wave scan over affine maps (compose prev then cur) ----
#pragma unroll
    for (int d = 1; d < 64; d <<= 1) {
        float Ap = __shfl_up(A, d);
        float Bp = __shfl_up(B, d);
        if (lane >= d) {
            B = fmaf(A, Bp, B);   // B = A_cur*B_prev + B_cur
            A = A * Ap;
        }
    }

    // ---- cross-wave scan (4 wave aggregates via LDS) ----
    __shared__ float sA[4], sB[4];
    if (lane == 63) { sA[wv] = A; sB[wv] = B; }
    __syncthreads();
    float E = 0.0f;                 // block-exclusive prefix value entering this wave
    if (wv > 0) {
        float Bacc = sB[0];
        for (int w = 1; w < wv; ++w) Bacc = fmaf(sA[w], Bacc, sB[w]);
        E = Bacc;
    }

    // ---- per-thread exclusive prefix: init = A_excl*E + B_excl ----
    float Ai = __shfl_up(A, 1);
    float Bi = __shfl_up(B, 1);
    if (lane == 0) { Ai = 1.0f; Bi = 0.0f; }
    float init = fmaf(Ai, E, Bi);

    // ---- replay with true init + PCEN epilogue ----
    sm = init;
#pragma unroll
    for (int j = 0; j < CHUNK; ++j) {
        float b = S_C * v[j];
        if (tid == 0 && j == 0) b = v[0];
        sm = fmaf(A_C, sm, b);
        // ratio = x / (sm+eps)^alpha  computed as x * exp2(-alpha*log2(sm+eps))
        float lg    = log2f(sm + EPS_C);
        float ratio = v[j] * exp2f(-ALPHA * lg);
        v[j] = sqrtf(ratio + 2.0f) - SQRT2;
    }

    if (active) {
        float4* __restrict__ o4 = (float4*)(out + base);
#pragma unroll
        for (int q = 0; q < 4; ++q) {
            float4 r;
            r.x = v[q * 4 + 0]; r.y = v[q * 4 + 1];
            r.z = v[q * 4 + 2]; r.w = v[q * 4 + 3];
            o4[tid * 4 + q] = r;
        }
    }
}

extern "C" void kernel_launch(void* const* d_in, const int* in_sizes, int n_in,
                              void* d_out, int out_size, void* d_ws, size_t ws_size,
                              hipStream_t stream) {
    const float* x   = (const float*)d_in[0];
    float*       out = (float*)d_out;
    const int nch = in_sizes[0] / TLEN;   // 64*128 = 8192 channels
    pcen_kernel<<<nch, NTH, 0, stream>>>(x, out);
}